// Round 8
// baseline (449.526 us; speedup 1.0000x reference)
//
#include <hip/hip_runtime.h>

typedef __attribute__((ext_vector_type(8))) short bf16x8;
typedef __attribute__((ext_vector_type(4))) float f32x4;
typedef __attribute__((ext_vector_type(4))) int   i32x4;

#define NROWS     131072
#define KCODES    1024
#define OUT_ELEMS 8388608
#define NBLK      1024              // 128 rows per block, 4 blocks/CU, one generation
#define MAGICF    12582912.0f       // 1.5 * 2^23
#define MARGIN    240               // key-quanta; >= 2x worst-case single-split screen err (~80)
// d_ws layout
#define WS_PART   0                 // 1024 doubles (8 KB)
#define WS_SE     (8*1024)          // 1024 f32 exact ||e||^2
#define WS_SEMG   (12*1024)         // 1024 f32: MAGICF + se*2^16  (MFMA acc-init values)
#define WS_BPREP  (16*1024)         // 64 chunks * 2 frags * 64 lanes * 16B = 128 KB

// numpy pairwise sum pattern for n=64 (exact fp32; round-2 verified).
__device__ __forceinline__ float pairwise64_sq(const float* __restrict__ v) {
#pragma clang fp contract(off)
    float r[8];
#pragma unroll
    for (int j = 0; j < 8; ++j) r[j] = v[j] * v[j];
#pragma unroll
    for (int i = 8; i < 64; i += 8) {
#pragma unroll
        for (int j = 0; j < 8; ++j) r[j] += v[i + j] * v[i + j];
    }
    return ((r[0] + r[1]) + (r[2] + r[3])) + ((r[4] + r[5]) + (r[6] + r[7]));
}

__device__ __forceinline__ int med3i(int a, int b, int c) {
    int mn = min(a, b), mx = max(a, b);
    return max(mn, min(mx, c));   // v_med3_i32
}

__device__ __forceinline__ unsigned short rne_bf16(float v) {
    unsigned u = __float_as_uint(v);
    return (unsigned short)((u + 0x7fffu + ((u >> 16) & 1u)) >> 16);
}

// One thread per code: exact se; acc-init table MAGICF + se*2^16; single-split
// bf16 B frags scaled by 2^8 (RNE). Frag layout: chunk c=k>>4, frag f=khalf,
// lane l=g*16+(k&15), elems j from d = f*32 + g*8 + j.
__global__ __launch_bounds__(256) void vq_prep(
    const float* __restrict__ emb, float* __restrict__ se,
    float* __restrict__ semg, unsigned short* __restrict__ bprep)
{
#pragma clang fp contract(off)
    const int k = blockIdx.x * 256 + threadIdx.x;
    if (k >= KCODES) return;
    const float* e = emb + (k << 6);
    float s = pairwise64_sq(e);
    se[k]   = s;
    semg[k] = MAGICF + s * 65536.0f;   // se*2^16 exact (pow2); one rounding on add

    const int c = k >> 4, slot = k & 15;
#pragma unroll
    for (int f = 0; f < 2; ++f) {
#pragma unroll
        for (int g = 0; g < 4; ++g) {
            unsigned short h[8];
#pragma unroll
            for (int j = 0; j < 8; ++j)
                h[j] = rne_bf16(e[f * 32 + g * 8 + j] * 256.0f);
            int4 w;
            w.x = h[0] | (h[1] << 16); w.y = h[2] | (h[3] << 16);
            w.z = h[4] | (h[5] << 16); w.w = h[6] | (h[7] << 16);
            *reinterpret_cast<int4*>(bprep + (((c * 2 + f) * 64 + (g * 16 + slot)) << 3)) = w;
        }
    }
}

__global__ __launch_bounds__(256, 4) void vq_main(
    const float* __restrict__ lat, const float* __restrict__ emb,
    const float* __restrict__ se_g, const float* __restrict__ semg_g,
    const unsigned short* __restrict__ bprep,
    float* __restrict__ out, double* __restrict__ partials)
{
#pragma clang fp contract(off)
    __shared__ int    keys_lds[128 * 49];  // 48 keys/row (top-3 x 16 cols)
    __shared__ int    idx_lds[128];
    __shared__ double wsum[4];

    const int tid = threadIdx.x, l = tid & 63, wv = tid >> 6;
    const int blk = blockIdx.x;
    const int n0 = blk * 128, b = n0 >> 12, hw0 = n0 & 4095;
    const float* latb = lat + ((size_t)b << 18) + hw0;   // element: latb[(d<<12) + row]

    // ---- A fragments straight from global: -2x * 2^8, RNE bf16 ----
    // A lane map (16x16x32): row = l&15, k = (l>>4)*8 + j.
    bf16x8 afrag[2][2];   // [tile][khalf]
    {
        const int arow = l & 15, kb = (l >> 4) << 3;
#pragma unroll
        for (int T = 0; T < 2; ++T) {
            const int row = wv * 32 + T * 16 + arow;
#pragma unroll
            for (int kh = 0; kh < 2; ++kh) {
                bf16x8 f;
#pragma unroll
                for (int j = 0; j < 8; ++j) {
                    float xv = latb[((size_t)(kh * 32 + kb + j) << 12) + row];
                    f[j] = (short)rne_bf16(xv * -512.0f);
                }
                afrag[T][kh] = f;
            }
        }
    }

    // ---- sweep 64 chunks of 16 codes: acc-init = magic+se*2^16, 4 MFMA,
    //      key = (bits(acc)<<10)|code (monotone signed), top-3 per (tile,reg) ----
    int m1[2][4], m2[2][4], m3[2][4];
#pragma unroll
    for (int T = 0; T < 2; ++T)
#pragma unroll
        for (int r = 0; r < 4; ++r) { m1[T][r] = m2[T][r] = m3[T][r] = 0x7fffffff; }

    const i32x4* bp = reinterpret_cast<const i32x4*>(bprep);
    i32x4 bbuf[2][2];
    float sbuf[2];
    bbuf[0][0] = bp[l];
    bbuf[0][1] = bp[64 + l];
    sbuf[0] = semg_g[l & 15];

#pragma unroll 2
    for (int c = 0; c < 64; ++c) {
        const int cur = c & 1, nxt = cur ^ 1;
        if (c < 63) {
            bbuf[nxt][0] = bp[(c + 1) * 128 + l];
            bbuf[nxt][1] = bp[(c + 1) * 128 + 64 + l];
            sbuf[nxt]    = semg_g[(c + 1) * 16 + (l & 15)];
        }
        bf16x8 b0 = __builtin_bit_cast(bf16x8, bbuf[cur][0]);
        bf16x8 b1 = __builtin_bit_cast(bf16x8, bbuf[cur][1]);
        const float sv = sbuf[cur];
        const unsigned code0 = (unsigned)((c << 4) + (l & 15));
#pragma unroll
        for (int T = 0; T < 2; ++T) {
            f32x4 acc = {sv, sv, sv, sv};
            acc = __builtin_amdgcn_mfma_f32_16x16x32_bf16(afrag[T][0], b0, acc, 0, 0, 0);
            acc = __builtin_amdgcn_mfma_f32_16x16x32_bf16(afrag[T][1], b1, acc, 0, 0, 0);
#pragma unroll
            for (int r = 0; r < 4; ++r) {
                // acc in [2^23,2^24): low-22 mantissa bits == (t*2^16) mod 2^22;
                // <<10 yields signed-monotone key for |t*2^16| < 2^21.
                int key = (int)((__float_as_uint(acc[r]) << 10) | code0);
                int n1 = min(key, m1[T][r]);
                int n2 = med3i(key, m1[T][r], m2[T][r]);
                int n3 = med3i(max(key, m1[T][r]), m2[T][r], m3[T][r]);
                m1[T][r] = n1; m2[T][r] = n2; m3[T][r] = n3;
            }
        }
    }

    // ---- dump top-3 keys (C map: row=(l>>4)*4+r, col=l&15) ----
#pragma unroll
    for (int T = 0; T < 2; ++T) {
#pragma unroll
        for (int r = 0; r < 4; ++r) {
            const int rloc = wv * 32 + T * 16 + ((l >> 4) << 2) + r;
            keys_lds[rloc * 49 + (l & 15) * 3 + 0] = m1[T][r];
            keys_lds[rloc * 49 + (l & 15) * 3 + 1] = m2[T][r];
            keys_lds[rloc * 49 + (l & 15) * 3 + 2] = m3[T][r];
        }
    }
    __syncthreads();

    // ---- finalize: 2 threads per row; exact fp32 re-check of in-margin keys ----
    {
        const int row = tid >> 1, half = tid & 1;
        const int kbase = row * 49 + half * 24;
        int mk = 0x7fffffff;
#pragma unroll 8
        for (int i = 0; i < 24; ++i) mk = min(mk, keys_lds[kbase + i]);
        mk = min(mk, __shfl_xor(mk, 1, 64));
        const int lim = mk + (MARGIN << 10) + 1023;

        // sx: numpy pairwise split across the pair (even: j=0..3, odd: j=4..7)
        const float* xg = latb + row;
        float rr[4];
        {
            const int j0 = half * 4;
            rr[0] = rr[1] = rr[2] = rr[3] = 0.0f;
#pragma unroll
            for (int i = 0; i < 64; i += 8) {
#pragma unroll
                for (int j = 0; j < 4; ++j) {
                    float v = xg[(size_t)(i + j0 + j) << 12];
                    rr[j] += v * v;
                }
            }
        }
        float part = (rr[0] + rr[1]) + (rr[2] + rr[3]);
        float sx;
        {
            float other = __shfl_xor(part, 1, 64);
            sx = half ? (other + part) : (part + other);   // ((r0..r3)) + ((r4..r7))
        }

        float bestd = 3.4e38f; int besti = KCODES;
        for (int i = 0; i < 24; ++i) {
            int key = keys_lds[kbase + i];
            if (key <= lim) {
                int code = key & 1023;
                const float* e = emb + (code << 6);
                float g = 0.0f;
#pragma unroll
                for (int d = 0; d < 64; ++d)
                    g = fmaf(xg[(size_t)d << 12], e[d], g);
                float s_   = sx + se_g[code];   // fl32
                float dist = s_ - 2.0f * g;     // 2g exact; fl32 subtract
                if (dist < bestd || (dist == bestd && code < besti)) { bestd = dist; besti = code; }
            }
        }
        float od = __shfl_xor(bestd, 1, 64);
        int   oi = __shfl_xor(besti, 1, 64);
        if (od < bestd || (od == bestd && oi < besti)) { bestd = od; besti = oi; }
        if (half == 0) idx_lds[row] = besti;
    }
    __syncthreads();

    // ---- epilogue: q_st (coalesced), inds, loss partial ----
    double lsum = 0.0;
    {
        const float aq = 1.0f / 8388608.0f;   // 2^-23 exactly
        const int row = tid & 127, dh = (tid >> 7) * 32;
        const int code = idx_lds[row];
        const float4* eq4 = reinterpret_cast<const float4*>(emb + (code << 6) + dh);
        const float* xg = latb + row;
        float* ob = out + ((size_t)b << 18) + hw0 + row;
#pragma unroll
        for (int qq = 0; qq < 8; ++qq) {
            float4 qv = eq4[qq];
            float qa[4] = {qv.x, qv.y, qv.z, qv.w};
#pragma unroll
            for (int u = 0; u < 4; ++u) {
                int d = dh + qq * 4 + u;
                float xv = xg[(size_t)d << 12];
                float qd = qa[u];
                float v  = (xv + aq * qd) + ((1.0f - aq) * qd - xv);
                ob[(size_t)d << 12] = v;
                float diff = qd - xv;
                lsum += (double)diff * (double)diff;
            }
        }
    }
    if (tid < 128) out[OUT_ELEMS + 1 + (size_t)n0 + tid] = (float)idx_lds[tid];

#pragma unroll
    for (int off = 32; off > 0; off >>= 1) lsum += __shfl_down(lsum, off, 64);
    if (l == 0) wsum[wv] = lsum;
    __syncthreads();
    if (tid == 0) partials[blk] = (wsum[0] + wsum[1]) + (wsum[2] + wsum[3]);
}

__global__ __launch_bounds__(512) void vq_finish(
    const double* __restrict__ partials, float* __restrict__ out)
{
    __shared__ double lds[8];
    const int t = threadIdx.x;
    double s = partials[t] + partials[t + 512];
#pragma unroll
    for (int off = 32; off > 0; off >>= 1) s += __shfl_down(s, off, 64);
    if ((t & 63) == 0) lds[t >> 6] = s;
    __syncthreads();
    if (t == 0) {
        double tot = 0.0;
#pragma unroll
        for (int i = 0; i < 8; ++i) tot += lds[i];
        out[OUT_ELEMS] = (float)(0.75 * tot / (double)OUT_ELEMS);
    }
}

extern "C" void kernel_launch(void* const* d_in, const int* in_sizes, int n_in,
                              void* d_out, int out_size, void* d_ws, size_t ws_size,
                              hipStream_t stream)
{
    const float* lat = (const float*)d_in[0];
    const float* emb = (const float*)d_in[1];
    float* out = (float*)d_out;
    char* ws = (char*)d_ws;

    double* partials      = (double*)(ws + WS_PART);
    float* se             = (float*)(ws + WS_SE);
    float* semg           = (float*)(ws + WS_SEMG);
    unsigned short* bprep = (unsigned short*)(ws + WS_BPREP);

    vq_prep<<<dim3(4),    dim3(256), 0, stream>>>(emb, se, semg, bprep);
    vq_main<<<dim3(NBLK), dim3(256), 0, stream>>>(lat, emb, se, semg, bprep, out, partials);
    vq_finish<<<dim3(1),  dim3(512), 0, stream>>>(partials, out);
}

// Round 9
// 209.157 us; speedup vs baseline: 2.1492x; 2.1492x over previous
//
#include <hip/hip_runtime.h>

typedef __attribute__((ext_vector_type(8))) short bf16x8;
typedef __attribute__((ext_vector_type(4))) float f32x4;
typedef __attribute__((ext_vector_type(4))) int   i32x4;

#define NROWS     131072
#define KCODES    1024
#define OUT_ELEMS 8388608
#define NBLK      1024              // 128 rows per block, one generation
#define MAGICF    12582912.0f       // 1.5 * 2^23
#define MARGIN    240               // key-quanta; >= 2x worst-case single-split screen err (~80)
// d_ws layout
#define WS_PART   0                 // 1024 doubles (8 KB)
#define WS_SE     (8*1024)          // 1024 f32 exact ||e||^2
#define WS_SEMG   (12*1024)         // 1024 f32: MAGICF + se*2^16  (MFMA acc-init values)
#define WS_BPREP  (16*1024)         // 64 chunks * 2 frags * 64 lanes * 16B = 128 KB

// numpy pairwise sum pattern for n=64 (exact fp32; round-2 verified).
__device__ __forceinline__ float pairwise64_sq(const float* __restrict__ v) {
#pragma clang fp contract(off)
    float r[8];
#pragma unroll
    for (int j = 0; j < 8; ++j) r[j] = v[j] * v[j];
#pragma unroll
    for (int i = 8; i < 64; i += 8) {
#pragma unroll
        for (int j = 0; j < 8; ++j) r[j] += v[i + j] * v[i + j];
    }
    return ((r[0] + r[1]) + (r[2] + r[3])) + ((r[4] + r[5]) + (r[6] + r[7]));
}

__device__ __forceinline__ int med3i(int a, int b, int c) {
    int mn = min(a, b), mx = max(a, b);
    return max(mn, min(mx, c));   // v_med3_i32
}

__device__ __forceinline__ unsigned short rne_bf16(float v) {
    unsigned u = __float_as_uint(v);
    return (unsigned short)((u + 0x7fffu + ((u >> 16) & 1u)) >> 16);
}

// One thread per code: exact se; acc-init table MAGICF + se*2^16; single-split
// bf16 B frags scaled by 2^8 (RNE). Frag layout: chunk c=k>>4, frag f=khalf,
// lane l=g*16+(k&15), elems j from d = f*32 + g*8 + j.
__global__ __launch_bounds__(256) void vq_prep(
    const float* __restrict__ emb, float* __restrict__ se,
    float* __restrict__ semg, unsigned short* __restrict__ bprep)
{
#pragma clang fp contract(off)
    const int k = blockIdx.x * 256 + threadIdx.x;
    if (k >= KCODES) return;
    const float* e = emb + (k << 6);
    float s = pairwise64_sq(e);
    se[k]   = s;
    semg[k] = MAGICF + s * 65536.0f;   // se*2^16 exact (pow2); one rounding on add

    const int c = k >> 4, slot = k & 15;
#pragma unroll
    for (int f = 0; f < 2; ++f) {
#pragma unroll
        for (int g = 0; g < 4; ++g) {
            unsigned short h[8];
#pragma unroll
            for (int j = 0; j < 8; ++j)
                h[j] = rne_bf16(e[f * 32 + g * 8 + j] * 256.0f);
            int4 w;
            w.x = h[0] | (h[1] << 16); w.y = h[2] | (h[3] << 16);
            w.z = h[4] | (h[5] << 16); w.w = h[6] | (h[7] << 16);
            *reinterpret_cast<int4*>(bprep + (((c * 2 + f) * 64 + (g * 16 + slot)) << 3)) = w;
        }
    }
}

// NOTE: min-waves=3 (NOT 4): at 4 the allocator clamps to the 64-VGPR granule
// and spills the sweep state into the hot loop (round-8: WRITE_SIZE +24 MB,
// 4.6x regression). At 3 the cap is ~168; natural use ~110 <= 128 still gives
// 4 waves/SIMD at runtime.
__global__ __launch_bounds__(256, 3) void vq_main(
    const float* __restrict__ lat, const float* __restrict__ emb,
    const float* __restrict__ se_g, const float* __restrict__ semg_g,
    const unsigned short* __restrict__ bprep,
    float* __restrict__ out, double* __restrict__ partials)
{
#pragma clang fp contract(off)
    __shared__ int    keys_lds[128 * 49];  // 48 keys/row (top-3 x 16 cols)
    __shared__ int    idx_lds[128];
    __shared__ double wsum[4];

    const int tid = threadIdx.x, l = tid & 63, wv = tid >> 6;
    const int blk = blockIdx.x;
    const int n0 = blk * 128, b = n0 >> 12, hw0 = n0 & 4095;
    const float* latb = lat + ((size_t)b << 18) + hw0;   // element: latb[(d<<12) + row]

    // ---- A fragments straight from global: -2x * 2^8, RNE bf16 ----
    // A lane map (16x16x32): row = l&15, k = (l>>4)*8 + j.
    bf16x8 afrag[2][2];   // [tile][khalf]
    {
        const int arow = l & 15, kb = (l >> 4) << 3;
#pragma unroll
        for (int T = 0; T < 2; ++T) {
            const int row = wv * 32 + T * 16 + arow;
#pragma unroll
            for (int kh = 0; kh < 2; ++kh) {
                bf16x8 f;
#pragma unroll
                for (int j = 0; j < 8; ++j) {
                    float xv = latb[((size_t)(kh * 32 + kb + j) << 12) + row];
                    f[j] = (short)rne_bf16(xv * -512.0f);
                }
                afrag[T][kh] = f;
            }
        }
    }

    // ---- sweep 64 chunks of 16 codes: acc-init = magic+se*2^16, 4 MFMA,
    //      key = (bits(acc)<<10)|code (monotone signed), top-3 per (tile,reg) ----
    int m1[2][4], m2[2][4], m3[2][4];
#pragma unroll
    for (int T = 0; T < 2; ++T)
#pragma unroll
        for (int r = 0; r < 4; ++r) { m1[T][r] = m2[T][r] = m3[T][r] = 0x7fffffff; }

    const i32x4* bp = reinterpret_cast<const i32x4*>(bprep);
    i32x4 bbuf[2][2];
    float sbuf[2];
    bbuf[0][0] = bp[l];
    bbuf[0][1] = bp[64 + l];
    sbuf[0] = semg_g[l & 15];

#pragma unroll 2
    for (int c = 0; c < 64; ++c) {
        const int cur = c & 1, nxt = cur ^ 1;
        if (c < 63) {
            bbuf[nxt][0] = bp[(c + 1) * 128 + l];
            bbuf[nxt][1] = bp[(c + 1) * 128 + 64 + l];
            sbuf[nxt]    = semg_g[(c + 1) * 16 + (l & 15)];
        }
        bf16x8 b0 = __builtin_bit_cast(bf16x8, bbuf[cur][0]);
        bf16x8 b1 = __builtin_bit_cast(bf16x8, bbuf[cur][1]);
        const float sv = sbuf[cur];
        const unsigned code0 = (unsigned)((c << 4) + (l & 15));
#pragma unroll
        for (int T = 0; T < 2; ++T) {
            f32x4 acc = {sv, sv, sv, sv};
            acc = __builtin_amdgcn_mfma_f32_16x16x32_bf16(afrag[T][0], b0, acc, 0, 0, 0);
            acc = __builtin_amdgcn_mfma_f32_16x16x32_bf16(afrag[T][1], b1, acc, 0, 0, 0);
#pragma unroll
            for (int r = 0; r < 4; ++r) {
                // acc in [2^23,2^24): low-22 mantissa bits == (t*2^16) mod 2^22;
                // <<10 yields signed-monotone key for |t*2^16| < 2^21.
                int key = (int)((__float_as_uint(acc[r]) << 10) | code0);
                int n1 = min(key, m1[T][r]);
                int n2 = med3i(key, m1[T][r], m2[T][r]);
                int n3 = med3i(max(key, m1[T][r]), m2[T][r], m3[T][r]);
                m1[T][r] = n1; m2[T][r] = n2; m3[T][r] = n3;
            }
        }
    }

    // ---- dump top-3 keys (C map: row=(l>>4)*4+r, col=l&15) ----
#pragma unroll
    for (int T = 0; T < 2; ++T) {
#pragma unroll
        for (int r = 0; r < 4; ++r) {
            const int rloc = wv * 32 + T * 16 + ((l >> 4) << 2) + r;
            keys_lds[rloc * 49 + (l & 15) * 3 + 0] = m1[T][r];
            keys_lds[rloc * 49 + (l & 15) * 3 + 1] = m2[T][r];
            keys_lds[rloc * 49 + (l & 15) * 3 + 2] = m3[T][r];
        }
    }
    __syncthreads();

    // ---- finalize: 2 threads per row; exact fp32 re-check of in-margin keys ----
    {
        const int row = tid >> 1, half = tid & 1;
        const int kbase = row * 49 + half * 24;
        int mk = 0x7fffffff;
#pragma unroll 8
        for (int i = 0; i < 24; ++i) mk = min(mk, keys_lds[kbase + i]);
        mk = min(mk, __shfl_xor(mk, 1, 64));
        const int lim = mk + (MARGIN << 10) + 1023;

        // sx: numpy pairwise split across the pair (even: j=0..3, odd: j=4..7)
        const float* xg = latb + row;
        float rr[4];
        {
            const int j0 = half * 4;
            rr[0] = rr[1] = rr[2] = rr[3] = 0.0f;
#pragma unroll
            for (int i = 0; i < 64; i += 8) {
#pragma unroll
                for (int j = 0; j < 4; ++j) {
                    float v = xg[(size_t)(i + j0 + j) << 12];
                    rr[j] += v * v;
                }
            }
        }
        float part = (rr[0] + rr[1]) + (rr[2] + rr[3]);
        float sx;
        {
            float other = __shfl_xor(part, 1, 64);
            sx = half ? (other + part) : (part + other);   // ((r0..r3)) + ((r4..r7))
        }

        float bestd = 3.4e38f; int besti = KCODES;
        for (int i = 0; i < 24; ++i) {
            int key = keys_lds[kbase + i];
            if (key <= lim) {
                int code = key & 1023;
                const float* e = emb + (code << 6);
                float g = 0.0f;
#pragma unroll
                for (int d = 0; d < 64; ++d)
                    g = fmaf(xg[(size_t)d << 12], e[d], g);
                float s_   = sx + se_g[code];   // fl32
                float dist = s_ - 2.0f * g;     // 2g exact; fl32 subtract
                if (dist < bestd || (dist == bestd && code < besti)) { bestd = dist; besti = code; }
            }
        }
        float od = __shfl_xor(bestd, 1, 64);
        int   oi = __shfl_xor(besti, 1, 64);
        if (od < bestd || (od == bestd && oi < besti)) { bestd = od; besti = oi; }
        if (half == 0) idx_lds[row] = besti;
    }
    __syncthreads();

    // ---- epilogue: q_st (coalesced), inds, loss partial ----
    double lsum = 0.0;
    {
        const float aq = 1.0f / 8388608.0f;   // 2^-23 exactly
        const int row = tid & 127, dh = (tid >> 7) * 32;
        const int code = idx_lds[row];
        const float4* eq4 = reinterpret_cast<const float4*>(emb + (code << 6) + dh);
        const float* xg = latb + row;
        float* ob = out + ((size_t)b << 18) + hw0 + row;
#pragma unroll
        for (int qq = 0; qq < 8; ++qq) {
            float4 qv = eq4[qq];
            float qa[4] = {qv.x, qv.y, qv.z, qv.w};
#pragma unroll
            for (int u = 0; u < 4; ++u) {
                int d = dh + qq * 4 + u;
                float xv = xg[(size_t)d << 12];
                float qd = qa[u];
                float v  = (xv + aq * qd) + ((1.0f - aq) * qd - xv);
                ob[(size_t)d << 12] = v;
                float diff = qd - xv;
                lsum += (double)diff * (double)diff;
            }
        }
    }
    if (tid < 128) out[OUT_ELEMS + 1 + (size_t)n0 + tid] = (float)idx_lds[tid];

#pragma unroll
    for (int off = 32; off > 0; off >>= 1) lsum += __shfl_down(lsum, off, 64);
    if (l == 0) wsum[wv] = lsum;
    __syncthreads();
    if (tid == 0) partials[blk] = (wsum[0] + wsum[1]) + (wsum[2] + wsum[3]);
}

__global__ __launch_bounds__(512) void vq_finish(
    const double* __restrict__ partials, float* __restrict__ out)
{
    __shared__ double lds[8];
    const int t = threadIdx.x;
    double s = partials[t] + partials[t + 512];
#pragma unroll
    for (int off = 32; off > 0; off >>= 1) s += __shfl_down(s, off, 64);
    if ((t & 63) == 0) lds[t >> 6] = s;
    __syncthreads();
    if (t == 0) {
        double tot = 0.0;
#pragma unroll
        for (int i = 0; i < 8; ++i) tot += lds[i];
        out[OUT_ELEMS] = (float)(0.75 * tot / (double)OUT_ELEMS);
    }
}

extern "C" void kernel_launch(void* const* d_in, const int* in_sizes, int n_in,
                              void* d_out, int out_size, void* d_ws, size_t ws_size,
                              hipStream_t stream)
{
    const float* lat = (const float*)d_in[0];
    const float* emb = (const float*)d_in[1];
    float* out = (float*)d_out;
    char* ws = (char*)d_ws;

    double* partials      = (double*)(ws + WS_PART);
    float* se             = (float*)(ws + WS_SE);
    float* semg           = (float*)(ws + WS_SEMG);
    unsigned short* bprep = (unsigned short*)(ws + WS_BPREP);

    vq_prep<<<dim3(4),    dim3(256), 0, stream>>>(emb, se, semg, bprep);
    vq_main<<<dim3(NBLK), dim3(256), 0, stream>>>(lat, emb, se, semg, bprep, out, partials);
    vq_finish<<<dim3(1),  dim3(512), 0, stream>>>(partials, out);
}

// Round 10
// 123.869 us; speedup vs baseline: 3.6290x; 1.6885x over previous
//
#include <hip/hip_runtime.h>

typedef __attribute__((ext_vector_type(8))) short bf16x8;
typedef __attribute__((ext_vector_type(4))) float f32x4;
typedef __attribute__((ext_vector_type(4))) int   i32x4;

#define NROWS     131072
#define KCODES    1024
#define OUT_ELEMS 8388608
#define NBLK      1024              // 128 rows per block, one generation
#define MAGICF    12582912.0f       // 1.5 * 2^23
#define MARGIN    240               // key-quanta; >= 2x worst-case single-split screen err
// d_ws layout
#define WS_PART   0                 // 1024 doubles (8 KB)
#define WS_SE     (8*1024)          // 1024 f32 exact ||e||^2
#define WS_SEMG   (12*1024)         // 1024 f32: MAGICF + se*2^16  (MFMA acc-init)
#define WS_BPREP  (16*1024)         // 64 chunks * 2 frags * 64 lanes * 16B = 128 KB

// numpy pairwise sum pattern for n=64 (exact fp32; round-2 verified).
__device__ __forceinline__ float pairwise64_sq(const float* __restrict__ v) {
#pragma clang fp contract(off)
    float r[8];
#pragma unroll
    for (int j = 0; j < 8; ++j) r[j] = v[j] * v[j];
#pragma unroll
    for (int i = 8; i < 64; i += 8) {
#pragma unroll
        for (int j = 0; j < 8; ++j) r[j] += v[i + j] * v[i + j];
    }
    return ((r[0] + r[1]) + (r[2] + r[3])) + ((r[4] + r[5]) + (r[6] + r[7]));
}

__device__ __forceinline__ int med3i(int a, int b, int c) {
    int mn = min(a, b), mx = max(a, b);
    return max(mn, min(mx, c));   // v_med3_i32
}

__device__ __forceinline__ unsigned short rne_bf16(float v) {
    unsigned u = __float_as_uint(v);
    return (unsigned short)((u + 0x7fffu + ((u >> 16) & 1u)) >> 16);
}

// One thread per code: exact se; acc-init table MAGICF + se*2^16; single-split
// bf16 B frags scaled by 2^8 (RNE). Frag layout: chunk c=k>>4, frag f=khalf,
// lane l=g*16+(k&15), elems j from d = f*32 + g*8 + j.
__global__ __launch_bounds__(256) void vq_prep(
    const float* __restrict__ emb, float* __restrict__ se,
    float* __restrict__ semg, unsigned short* __restrict__ bprep)
{
#pragma clang fp contract(off)
    const int k = blockIdx.x * 256 + threadIdx.x;
    if (k >= KCODES) return;
    const float* e = emb + (k << 6);
    float s = pairwise64_sq(e);
    se[k]   = s;
    semg[k] = MAGICF + s * 65536.0f;

    const int c = k >> 4, slot = k & 15;
#pragma unroll
    for (int f = 0; f < 2; ++f) {
#pragma unroll
        for (int g = 0; g < 4; ++g) {
            unsigned short h[8];
#pragma unroll
            for (int j = 0; j < 8; ++j)
                h[j] = rne_bf16(e[f * 32 + g * 8 + j] * 256.0f);
            int4 w;
            w.x = h[0] | (h[1] << 16); w.y = h[2] | (h[3] << 16);
            w.z = h[4] | (h[5] << 16); w.w = h[6] | (h[7] << 16);
            *reinterpret_cast<int4*>(bprep + (((c * 2 + f) * 64 + (g * 16 + slot)) << 3)) = w;
        }
    }
}

// min-waves=3, NOT 4: round-8 showed 4 clamps to the 64-VGPR granule and
// spills the sweep state (WRITE_SIZE +24 MB, 4.6x). Natural use ~100 VGPR.
__global__ __launch_bounds__(256, 3) void vq_main(
    const float* __restrict__ lat, const float* __restrict__ emb,
    const float* __restrict__ se_g, const float* __restrict__ semg_g,
    const unsigned short* __restrict__ bprep,
    float* __restrict__ out, double* __restrict__ partials)
{
#pragma clang fp contract(off)
    __shared__ float  x_lds[128 * 67];   // 34.3 KB; total ~39 KB -> 4 blocks/CU
    __shared__ int    idx_lds[128];
    __shared__ double wsum[4];

    const int tid = threadIdx.x, l = tid & 63, wv = tid >> 6;
    const int blk = blockIdx.x;
    const int n0 = blk * 128, b = n0 >> 12, hw0 = n0 & 4095;
    const float* latb = lat + ((size_t)b << 18) + hw0;   // element: latb[(d<<12)+row]

    // ---- stage x: float4 along hw (coalesced, 8 vmem/thread) ----
    {
        const float4* lat4 = reinterpret_cast<const float4*>(latb);
#pragma unroll
        for (int it = 0; it < 8; ++it) {
            int idx = it * 256 + tid;        // 0..2047
            int d = idx >> 5, hwg = idx & 31;
            float4 v = lat4[(size_t)d * 1024 + hwg];
            int row = hwg * 4;
            x_lds[(row + 0) * 67 + d] = v.x;
            x_lds[(row + 1) * 67 + d] = v.y;
            x_lds[(row + 2) * 67 + d] = v.z;
            x_lds[(row + 3) * 67 + d] = v.w;
        }
    }
    __syncthreads();

    // ---- A fragments from LDS: -2x * 2^8, RNE bf16 (row=l&15, k=(l>>4)*8+j) ----
    bf16x8 afrag[2][2];   // [tile][khalf]
    {
        const int arow = l & 15, kb = (l >> 4) << 3;
#pragma unroll
        for (int T = 0; T < 2; ++T) {
            const float* xr = x_lds + (wv * 32 + T * 16 + arow) * 67;
#pragma unroll
            for (int kh = 0; kh < 2; ++kh) {
                bf16x8 f;
#pragma unroll
                for (int j = 0; j < 8; ++j)
                    f[j] = (short)rne_bf16(xr[kh * 32 + kb + j] * -512.0f);
                afrag[T][kh] = f;
            }
        }
    }

    // ---- sweep 64 chunks: acc-init = magic+se*2^16, 4 MFMA/chunk,
    //      key = (bits(acc)<<10)|code (signed-monotone), top-3 per (T,reg) ----
    int m1[2][4], m2[2][4], m3[2][4];
#pragma unroll
    for (int T = 0; T < 2; ++T)
#pragma unroll
        for (int r = 0; r < 4; ++r) { m1[T][r] = m2[T][r] = m3[T][r] = 0x7fffffff; }

    const i32x4* bp = reinterpret_cast<const i32x4*>(bprep);
    i32x4 bbuf[2][2];
    float sbuf[2];
    bbuf[0][0] = bp[l];
    bbuf[0][1] = bp[64 + l];
    sbuf[0] = semg_g[l & 15];

#pragma unroll 2
    for (int c = 0; c < 64; ++c) {
        const int cur = c & 1, nxt = cur ^ 1;
        if (c < 63) {
            bbuf[nxt][0] = bp[(c + 1) * 128 + l];
            bbuf[nxt][1] = bp[(c + 1) * 128 + 64 + l];
            sbuf[nxt]    = semg_g[(c + 1) * 16 + (l & 15)];
        }
        bf16x8 b0 = __builtin_bit_cast(bf16x8, bbuf[cur][0]);
        bf16x8 b1 = __builtin_bit_cast(bf16x8, bbuf[cur][1]);
        const float sv = sbuf[cur];
        const unsigned code0 = (unsigned)((c << 4) + (l & 15));
#pragma unroll
        for (int T = 0; T < 2; ++T) {
            f32x4 acc = {sv, sv, sv, sv};
            acc = __builtin_amdgcn_mfma_f32_16x16x32_bf16(afrag[T][0], b0, acc, 0, 0, 0);
            acc = __builtin_amdgcn_mfma_f32_16x16x32_bf16(afrag[T][1], b1, acc, 0, 0, 0);
#pragma unroll
            for (int r = 0; r < 4; ++r) {
                int key = (int)((__float_as_uint(acc[r]) << 10) | code0);
                int n1 = min(key, m1[T][r]);
                int n2 = med3i(key, m1[T][r], m2[T][r]);
                int n3 = med3i(max(key, m1[T][r]), m2[T][r], m3[T][r]);
                m1[T][r] = n1; m2[T][r] = n2; m3[T][r] = n3;
            }
        }
    }

    // ---- wave-local finalize: no keys_lds, no barrier.
    //      Row (T,r,g)=wv*32+T*16+g*4+r lives on the 16 lanes with l>>4==g. ----
    {
        const int col = l & 15, cj = col & 7;
#pragma unroll
        for (int T = 0; T < 2; ++T) {
#pragma unroll
            for (int r = 0; r < 4; ++r) {
                const int row = wv * 32 + T * 16 + ((l >> 4) << 2) + r;
                const float* xr = x_lds + row * 67;

                // row-min of screen keys across the 16 columns
                int mk = m1[T][r];
#pragma unroll
                for (int off = 1; off < 16; off <<= 1)
                    mk = min(mk, __shfl_xor(mk, off, 64));
                const int lim = mk + (MARGIN << 10) + 1023;

                // sx: numpy-exact pairwise via 8-lane butterfly (lanes 8-15 mirror)
                float rj = 0.0f;
#pragma unroll
                for (int i = 0; i < 64; i += 8) {
                    float v = xr[i + cj];
                    rj += v * v;       // serial 8-term chain == numpy r[cj]
                }
                float sx = rj;
#pragma unroll
                for (int off = 1; off < 8; off <<= 1)
                    sx += __shfl_xor(sx, off, 64);   // exact numpy combine tree

                // exact fp32 re-check of this lane's in-margin keys
                float bestd = 3.4e38f; int besti = KCODES;
                int mykeys0 = m1[T][r], mykeys1 = m2[T][r], mykeys2 = m3[T][r];
#pragma unroll
                for (int kk = 0; kk < 3; ++kk) {
                    int key = (kk == 0) ? mykeys0 : (kk == 1) ? mykeys1 : mykeys2;
                    if (key <= lim) {
                        int code = key & 1023;
                        const float* e = emb + (code << 6);
                        float gacc = 0.0f;
#pragma unroll
                        for (int d = 0; d < 64; ++d)
                            gacc = fmaf(xr[d], e[d], gacc);
                        float s_   = sx + se_g[code];   // fl32
                        float dist = s_ - 2.0f * gacc;  // 2g exact; fl32 subtract
                        if (dist < bestd || (dist == bestd && code < besti)) {
                            bestd = dist; besti = code;
                        }
                    }
                }
                // winner across 16 columns, first-index tie-break (np.argmin)
#pragma unroll
                for (int off = 1; off < 16; off <<= 1) {
                    float od = __shfl_xor(bestd, off, 64);
                    int   oi = __shfl_xor(besti, off, 64);
                    if (od < bestd || (od == bestd && oi < besti)) { bestd = od; besti = oi; }
                }
                if (col == 0) {
                    idx_lds[row] = besti;
                    out[OUT_ELEMS + 1 + (size_t)n0 + row] = (float)besti;
                }
            }
        }
    }
    __syncthreads();

    // ---- epilogue: q_st (coalesced), loss partial ----
    double lsum = 0.0;
    {
        const float aq = 1.0f / 8388608.0f;   // 2^-23 exactly
        const int row = tid & 127, dh = (tid >> 7) * 32;
        const int code = idx_lds[row];
        const float4* eq4 = reinterpret_cast<const float4*>(emb + (code << 6) + dh);
        const float* xr = x_lds + row * 67;
        float* ob = out + ((size_t)b << 18) + hw0 + row;
#pragma unroll
        for (int qq = 0; qq < 8; ++qq) {
            float4 qv = eq4[qq];
            float qa[4] = {qv.x, qv.y, qv.z, qv.w};
#pragma unroll
            for (int u = 0; u < 4; ++u) {
                int d = dh + qq * 4 + u;
                float xv = xr[d];
                float qd = qa[u];
                float v  = (xv + aq * qd) + ((1.0f - aq) * qd - xv);
                ob[(size_t)d << 12] = v;
                float diff = qd - xv;
                lsum += (double)diff * (double)diff;
            }
        }
    }

#pragma unroll
    for (int off = 32; off > 0; off >>= 1) lsum += __shfl_down(lsum, off, 64);
    if (l == 0) wsum[wv] = lsum;
    __syncthreads();
    if (tid == 0) partials[blk] = (wsum[0] + wsum[1]) + (wsum[2] + wsum[3]);
}

__global__ __launch_bounds__(512) void vq_finish(
    const double* __restrict__ partials, float* __restrict__ out)
{
    __shared__ double lds[8];
    const int t = threadIdx.x;
    double s = partials[t] + partials[t + 512];
#pragma unroll
    for (int off = 32; off > 0; off >>= 1) s += __shfl_down(s, off, 64);
    if ((t & 63) == 0) lds[t >> 6] = s;
    __syncthreads();
    if (t == 0) {
        double tot = 0.0;
#pragma unroll
        for (int i = 0; i < 8; ++i) tot += lds[i];
        out[OUT_ELEMS] = (float)(0.75 * tot / (double)OUT_ELEMS);
    }
}

extern "C" void kernel_launch(void* const* d_in, const int* in_sizes, int n_in,
                              void* d_out, int out_size, void* d_ws, size_t ws_size,
                              hipStream_t stream)
{
    const float* lat = (const float*)d_in[0];
    const float* emb = (const float*)d_in[1];
    float* out = (float*)d_out;
    char* ws = (char*)d_ws;

    double* partials      = (double*)(ws + WS_PART);
    float* se             = (float*)(ws + WS_SE);
    float* semg           = (float*)(ws + WS_SEMG);
    unsigned short* bprep = (unsigned short*)(ws + WS_BPREP);

    vq_prep<<<dim3(4),    dim3(256), 0, stream>>>(emb, se, semg, bprep);
    vq_main<<<dim3(NBLK), dim3(256), 0, stream>>>(lat, emb, se, semg, bprep, out, partials);
    vq_finish<<<dim3(1),  dim3(512), 0, stream>>>(partials, out);
}